// Round 8
// baseline (1099.251 us; speedup 1.0000x reference)
//
#include <hip/hip_runtime.h>
#include <hip/hip_fp16.h>

// Problem: B=64, T=512, IN=1024, H=1024, NH=4, HD=256, NG=3
// out h: [B,T,H] then hn: [1,B,H]  (fp32)

typedef _Float16 f16x8 __attribute__((ext_vector_type(8)));
typedef _Float16 f16x2 __attribute__((ext_vector_type(2)));
typedef float    f32x4 __attribute__((ext_vector_type(4)));

#define AS1 __attribute__((address_space(1)))
#define AS3 __attribute__((address_space(3)))

__device__ __forceinline__ void async_ld16(const void* g, void* l) {
    __builtin_amdgcn_global_load_lds((const AS1 void*)g, (AS3 void*)l, 16, 0, 0);
}

__device__ __forceinline__ float sigmoidf_(float x) {
    return 1.f / (1.f + __expf(-x));
}
__device__ __forceinline__ float tanhf_(float x) {
    float e = __expf(-2.f * fabsf(x));
    float r = (1.f - e) / (1.f + e);
    return copysignf(r, x);
}

// f32 += dot(f16x2, f16x2). Plain "v": legal only if operands are arch VGPRs.
// Register-file model (R2-R7 post-mortems): unified pool = 512 regs/wave-slot
// per SIMD. 1024-thr blocks (4 waves/SIMD) cap 128/wave -> Rr can't be arch.
// 512-thr blocks cap 256/wave; waves_per_eu(1,2) licenses the 2-waves/EU
// target so the allocator may use ~256 arch regs -> Rr in VGPRs, no moves.
__device__ __forceinline__ float dot2f(f16x2 a, f16x2 b, float c) {
    asm("v_dot2_f32_f16 %0, %1, %2, %0" : "+v"(c) : "v"(a), "v"(b));
    return c;
}

// ---- input f32 -> f16 (vectorized) ----
__global__ __launch_bounds__(256) void cast_to_f16(const float* __restrict__ in,
                                                   _Float16* __restrict__ out, int n8) {
    int i = blockIdx.x * 256 + threadIdx.x;
    if (i >= n8) return;
    const float4* p = (const float4*)in;
    float4 a = p[2 * i], b = p[2 * i + 1];
    f16x8 r;
    r[0] = (_Float16)a.x; r[1] = (_Float16)a.y; r[2] = (_Float16)a.z; r[3] = (_Float16)a.w;
    r[4] = (_Float16)b.x; r[5] = (_Float16)b.y; r[6] = (_Float16)b.z; r[7] = (_Float16)b.w;
    *(f16x8*)(out + (size_t)i * 8) = r;
}

// ---- W [1024,3072] f32 -> W^T [3072,1024] f16 ----
__global__ __launch_bounds__(256) void transpose_cast(const float* __restrict__ W,
                                                      _Float16* __restrict__ WT) {
    __shared__ float tile[32][33];
    const int tx = threadIdx.x, ty = threadIdx.y;
    const int n0 = blockIdx.x * 32, k0 = blockIdx.y * 32;
#pragma unroll
    for (int j = 0; j < 32; j += 8)
        tile[ty + j][tx] = W[(size_t)(k0 + ty + j) * 3072 + n0 + tx];
    __syncthreads();
#pragma unroll
    for (int j = 0; j < 32; j += 8)
        WT[(size_t)(n0 + ty + j) * 1024 + k0 + tx] = (_Float16)tile[tx][ty + j];
}

// ---- GEMM: Wx[t][b][head][g][o] = (input @ W)[m=b*512+t][n] + bW[n] + bR[head][g][o]
__global__ __launch_bounds__(256) void gemm_wx(const _Float16* __restrict__ A,
                                               const _Float16* __restrict__ BT,
                                               const float* __restrict__ bW,
                                               const float* __restrict__ bR,
                                               float* __restrict__ Wx) {
    __shared__ _Float16 As[128 * 32];
    __shared__ _Float16 Bs[128 * 32];
    const int tid  = threadIdx.x;
    const int wave = tid >> 6, lane = tid & 63;
    const int m0 = blockIdx.y * 128, n0 = blockIdx.x * 128;
    const int wm = (wave >> 1) * 64, wn = (wave & 1) * 64;
    const int r16 = lane & 15, kq = lane >> 4;

    f32x4 acc[4][4];
#pragma unroll
    for (int m = 0; m < 4; m++)
#pragma unroll
        for (int n = 0; n < 4; n++) acc[m][n] = (f32x4){0.f, 0.f, 0.f, 0.f};

    const int srow = wave * 32 + (lane >> 2);
    const int scol = (lane & 3) * 8;

    for (int kt = 0; kt < 32; kt++) {
        const int k0 = kt * 32;
#pragma unroll
        for (int j = 0; j < 2; j++) {
            async_ld16(A  + (size_t)(m0 + srow + j * 16) * 1024 + k0 + scol,
                       As + (wave * 32 + j * 16) * 32);
            async_ld16(BT + (size_t)(n0 + srow + j * 16) * 1024 + k0 + scol,
                       Bs + (wave * 32 + j * 16) * 32);
        }
        __syncthreads();
        f16x8 af[4], bf[4];
#pragma unroll
        for (int m = 0; m < 4; m++) af[m] = *(const f16x8*)(As + (wm + m * 16 + r16) * 32 + kq * 8);
#pragma unroll
        for (int n = 0; n < 4; n++) bf[n] = *(const f16x8*)(Bs + (wn + n * 16 + r16) * 32 + kq * 8);
#pragma unroll
        for (int m = 0; m < 4; m++)
#pragma unroll
            for (int n = 0; n < 4; n++)
                acc[m][n] = __builtin_amdgcn_mfma_f32_16x16x32_f16(af[m], bf[n], acc[m][n], 0, 0, 0);
        __syncthreads();
    }

#pragma unroll
    for (int m = 0; m < 4; m++) {
        const int row0 = m0 + wm + m * 16 + (lane >> 4) * 4;
#pragma unroll
        for (int n = 0; n < 4; n++) {
            const int col  = n0 + wn + n * 16 + r16;
            const int g    = col >> 10, head = (col >> 8) & 3, o = col & 255;
            const float bias = bW[col] + bR[head * 768 + g * 256 + o];
#pragma unroll
            for (int q = 0; q < 4; q++) {
                const int rr = row0 + q;
                const int t = rr & 511, bb = rr >> 9;
                Wx[(((size_t)t * 64 + bb) * 12 + head * 3 + g) * 256 + o] = acc[m][n][q] + bias;
            }
        }
    }
}

// ---- persistent scan: one block per (b, head); 512 steps internal ----
// 512 threads: o = t&255, ih = t>>8 (K-half, wave-uniform). Rr = 3x64 f16x2 =
// 192 regs/thread, arch-VGPR-resident under the 256/wave budget granted by
// waves_per_eu(1,2) (2 waves/SIMD at 1 block/CU). Zero AGPR move tax.
__global__ __attribute__((amdgpu_waves_per_eu(1, 2)))
__launch_bounds__(512) void scan_persist(const float* __restrict__ R,
                                         const float* __restrict__ Wx,
                                         float* __restrict__ out) {
    const int head = blockIdx.x >> 6;
    const int b    = blockIdx.x & 63;
    const int t    = threadIdx.x;
    const int o    = t & 255;
    const int ih   = t >> 8;  // 0/1, wave-uniform

    __shared__ _Float16 h16[256];
    __shared__ float red[2][3][256];

    // ---- load R[head][i][g][o] for i in [ih*128, ih*128+128), all g, my o ----
    f16x2 Rr[3][64];
    {
        const float* Rb = R + (((size_t)head * 256 + ih * 128) * 3) * 256 + o;
#pragma unroll
        for (int i2 = 0; i2 < 64; i2++) {
#pragma unroll
            for (int g = 0; g < 3; g++) {
                const float lo = Rb[((size_t)(2 * i2) * 3 + g) * 256];
                const float hi = Rb[((size_t)(2 * i2 + 1) * 3 + g) * 256];
                f16x2 p; p[0] = (_Float16)lo; p[1] = (_Float16)hi;
                Rr[g][i2] = p;
            }
        }
    }

    float hreg = 0.f;                      // fp32 carry for my o (threads t<256)
    float wxc0 = 0.f, wxc1 = 0.f, wxc2 = 0.f;
    if (t < 256) {
        const float* p = Wx + ((size_t)b * 12 + head * 3) * 256 + o;  // step 0
        wxc0 = p[0]; wxc1 = p[256]; wxc2 = p[512];
        h16[o] = (_Float16)0.f;
    }
    __syncthreads();

    float* outp = out + (size_t)b * 512 * 1024 + head * 256 + o;

    for (int step = 0; step < 512; step++) {
        // prefetch next step's wx (hidden under the dot loop)
        float wxn0 = 0.f, wxn1 = 0.f, wxn2 = 0.f;
        if (t < 256 && step < 511) {
            const float* p = Wx + (((size_t)(step + 1) * 64 + b) * 12 + head * 3) * 256 + o;
            wxn0 = p[0]; wxn1 = p[256]; wxn2 = p[512];
        }
        // ry partials over my K-half: 192 v_dot2_f32_f16 (h reads wave-broadcast)
        float az = 0.f, ar = 0.f, an = 0.f;
        const f16x8* hp = (const f16x8*)(h16 + ih * 128);
#pragma unroll
        for (int k = 0; k < 16; k++) {
            union { f16x8 v; f16x2 p[4]; } u;
            u.v = hp[k];
#pragma unroll
            for (int j = 0; j < 4; j++) {
                az = dot2f(Rr[0][k * 4 + j], u.p[j], az);
                ar = dot2f(Rr[1][k * 4 + j], u.p[j], ar);
                an = dot2f(Rr[2][k * 4 + j], u.p[j], an);
            }
        }
        red[ih][0][o] = az; red[ih][1][o] = ar; red[ih][2][o] = an;
        __syncthreads();
        if (t < 256) {
            const float z  = sigmoidf_(wxc0 + red[0][0][o] + red[1][0][o]);
            const float r  = sigmoidf_(wxc1 + red[0][1][o] + red[1][1][o]);
            const float n  = tanhf_(wxc2 + r * (red[0][2][o] + red[1][2][o]));
            const float hn = z * hreg + (1.f - z) * n;
            hreg = hn;
            outp[(size_t)step * 1024] = hn;
            h16[o] = (_Float16)hn;
        }
        wxc0 = wxn0; wxc1 = wxn1; wxc2 = wxn2;
        __syncthreads();
    }
}

// ---- hn = h[:, T-1, :] ----
__global__ __launch_bounds__(256) void copy_hn(float* __restrict__ out) {
    const int idx = blockIdx.x * 256 + threadIdx.x;  // 65536
    out[(size_t)64 * 512 * 1024 + idx] =
        out[((size_t)(idx >> 10) * 512 + 511) * 1024 + (idx & 1023)];
}

extern "C" void kernel_launch(void* const* d_in, const int* in_sizes, int n_in,
                              void* d_out, int out_size, void* d_ws, size_t ws_size,
                              hipStream_t stream) {
    (void)in_sizes; (void)n_in; (void)out_size; (void)ws_size;
    const float* inp = (const float*)d_in[0];
    const float* W   = (const float*)d_in[1];
    const float* bW  = (const float*)d_in[2];
    const float* R   = (const float*)d_in[3];
    const float* bR  = (const float*)d_in[4];
    float* out = (float*)d_out;

    // ws layout: A16 (64 MiB) | WT (6 MiB) | Wx f32 (384 MiB)
    _Float16* A16 = (_Float16*)d_ws;
    _Float16* WT  = (_Float16*)((char*)d_ws + 67108864);
    float*    Wx  = (float*)((char*)d_ws + 73400320);

    cast_to_f16<<<16384, 256, 0, stream>>>(inp, A16, 4194304);
    transpose_cast<<<dim3(96, 32), dim3(32, 8), 0, stream>>>(W, WT);
    gemm_wx<<<dim3(24, 256), 256, 0, stream>>>(A16, WT, bW, bR, Wx);
    scan_persist<<<256, 512, 0, stream>>>(R, Wx, out);
    copy_hn<<<256, 256, 0, stream>>>(out);
}

// Round 9
// 1074.333 us; speedup vs baseline: 1.0232x; 1.0232x over previous
//
#include <hip/hip_runtime.h>
#include <hip/hip_fp16.h>

// Problem: B=64, T=512, IN=1024, H=1024, NH=4, HD=256, NG=3
// out h: [B,T,H] then hn: [1,B,H]  (fp32)

typedef _Float16 f16x8 __attribute__((ext_vector_type(8)));
typedef _Float16 f16x2 __attribute__((ext_vector_type(2)));
typedef float    f32x4 __attribute__((ext_vector_type(4)));

#define AS1 __attribute__((address_space(1)))
#define AS3 __attribute__((address_space(3)))

__device__ __forceinline__ void async_ld16(const void* g, void* l) {
    __builtin_amdgcn_global_load_lds((const AS1 void*)g, (AS3 void*)l, 16, 0, 0);
}

__device__ __forceinline__ float sigmoidf_(float x) {
    return 1.f / (1.f + __expf(-x));
}
__device__ __forceinline__ float tanhf_(float x) {
    float e = __expf(-2.f * fabsf(x));
    float r = (1.f - e) / (1.f + e);
    return copysignf(r, x);
}

// f32 += dot(f16x2, f16x2) — builtin ONLY, deliberately NO inline asm anywhere
// in the scan kernel: a function with no MFMA and no asm gets LLVM's
// "amdgpu-no-agpr" inference, so the register allocator may hand the WHOLE
// unified 256-reg/wave budget (at 2 waves/SIMD) to arch VGPRs. R8 post-mortem:
// with inline asm present the allocator reserved the AGPR half (128+128) and
// paid one v_accvgpr_read per dot2 (~768 cyc/SIMD/step move tax).
#if defined(__has_builtin)
#if __has_builtin(__builtin_amdgcn_fdot2)
#define HAVE_FDOT2 1
#endif
#endif
__device__ __forceinline__ float dot2f(f16x2 a, f16x2 b, float c) {
#ifdef HAVE_FDOT2
    return __builtin_amdgcn_fdot2(a, b, c, false);
#else
    return c + (float)a[0] * (float)b[0] + (float)a[1] * (float)b[1];
#endif
}

// ---- input f32 -> f16 (vectorized) ----
__global__ __launch_bounds__(256) void cast_to_f16(const float* __restrict__ in,
                                                   _Float16* __restrict__ out, int n8) {
    int i = blockIdx.x * 256 + threadIdx.x;
    if (i >= n8) return;
    const float4* p = (const float4*)in;
    float4 a = p[2 * i], b = p[2 * i + 1];
    f16x8 r;
    r[0] = (_Float16)a.x; r[1] = (_Float16)a.y; r[2] = (_Float16)a.z; r[3] = (_Float16)a.w;
    r[4] = (_Float16)b.x; r[5] = (_Float16)b.y; r[6] = (_Float16)b.z; r[7] = (_Float16)b.w;
    *(f16x8*)(out + (size_t)i * 8) = r;
}

// ---- W [1024,3072] f32 -> W^T [3072,1024] f16 ----
__global__ __launch_bounds__(256) void transpose_cast(const float* __restrict__ W,
                                                      _Float16* __restrict__ WT) {
    __shared__ float tile[32][33];
    const int tx = threadIdx.x, ty = threadIdx.y;
    const int n0 = blockIdx.x * 32, k0 = blockIdx.y * 32;
#pragma unroll
    for (int j = 0; j < 32; j += 8)
        tile[ty + j][tx] = W[(size_t)(k0 + ty + j) * 3072 + n0 + tx];
    __syncthreads();
#pragma unroll
    for (int j = 0; j < 32; j += 8)
        WT[(size_t)(n0 + ty + j) * 1024 + k0 + tx] = (_Float16)tile[tx][ty + j];
}

// ---- GEMM: Wx[t][b][head][g][o] = (input @ W)[m=b*512+t][n] + bW[n] + bR[head][g][o]
__global__ __launch_bounds__(256) void gemm_wx(const _Float16* __restrict__ A,
                                               const _Float16* __restrict__ BT,
                                               const float* __restrict__ bW,
                                               const float* __restrict__ bR,
                                               float* __restrict__ Wx) {
    __shared__ _Float16 As[128 * 32];
    __shared__ _Float16 Bs[128 * 32];
    const int tid  = threadIdx.x;
    const int wave = tid >> 6, lane = tid & 63;
    const int m0 = blockIdx.y * 128, n0 = blockIdx.x * 128;
    const int wm = (wave >> 1) * 64, wn = (wave & 1) * 64;
    const int r16 = lane & 15, kq = lane >> 4;

    f32x4 acc[4][4];
#pragma unroll
    for (int m = 0; m < 4; m++)
#pragma unroll
        for (int n = 0; n < 4; n++) acc[m][n] = (f32x4){0.f, 0.f, 0.f, 0.f};

    const int srow = wave * 32 + (lane >> 2);
    const int scol = (lane & 3) * 8;

    for (int kt = 0; kt < 32; kt++) {
        const int k0 = kt * 32;
#pragma unroll
        for (int j = 0; j < 2; j++) {
            async_ld16(A  + (size_t)(m0 + srow + j * 16) * 1024 + k0 + scol,
                       As + (wave * 32 + j * 16) * 32);
            async_ld16(BT + (size_t)(n0 + srow + j * 16) * 1024 + k0 + scol,
                       Bs + (wave * 32 + j * 16) * 32);
        }
        __syncthreads();
        f16x8 af[4], bf[4];
#pragma unroll
        for (int m = 0; m < 4; m++) af[m] = *(const f16x8*)(As + (wm + m * 16 + r16) * 32 + kq * 8);
#pragma unroll
        for (int n = 0; n < 4; n++) bf[n] = *(const f16x8*)(Bs + (wn + n * 16 + r16) * 32 + kq * 8);
#pragma unroll
        for (int m = 0; m < 4; m++)
#pragma unroll
            for (int n = 0; n < 4; n++)
                acc[m][n] = __builtin_amdgcn_mfma_f32_16x16x32_f16(af[m], bf[n], acc[m][n], 0, 0, 0);
        __syncthreads();
    }

#pragma unroll
    for (int m = 0; m < 4; m++) {
        const int row0 = m0 + wm + m * 16 + (lane >> 4) * 4;
#pragma unroll
        for (int n = 0; n < 4; n++) {
            const int col  = n0 + wn + n * 16 + r16;
            const int g    = col >> 10, head = (col >> 8) & 3, o = col & 255;
            const float bias = bW[col] + bR[head * 768 + g * 256 + o];
#pragma unroll
            for (int q = 0; q < 4; q++) {
                const int rr = row0 + q;
                const int t = rr & 511, bb = rr >> 9;
                Wx[(((size_t)t * 64 + bb) * 12 + head * 3 + g) * 256 + o] = acc[m][n][q] + bias;
            }
        }
    }
}

// ---- persistent scan: one block per (b, head); 512 steps internal ----
// 512 threads: o = t&255, ih = t>>8 (K-half, wave-uniform). Rr = 3x64 f16x2 =
// 192 regs/thread. Asm-free kernel + waves_per_eu(2,2) => "amdgpu-no-agpr" +
// a pinned 256-reg/wave budget: Rr lives in arch VGPRs, zero move tax.
__global__ __attribute__((amdgpu_waves_per_eu(2, 2)))
__launch_bounds__(512) void scan_persist(const float* __restrict__ R,
                                         const float* __restrict__ Wx,
                                         float* __restrict__ out) {
    const int head = blockIdx.x >> 6;
    const int b    = blockIdx.x & 63;
    const int t    = threadIdx.x;
    const int o    = t & 255;
    const int ih   = t >> 8;  // 0/1, wave-uniform

    __shared__ _Float16 h16[256];
    __shared__ float red[2][3][256];

    // ---- load R[head][i][g][o] for i in [ih*128, ih*128+128), all g, my o ----
    f16x2 Rr[3][64];
    {
        const float* Rb = R + (((size_t)head * 256 + ih * 128) * 3) * 256 + o;
#pragma unroll
        for (int i2 = 0; i2 < 64; i2++) {
#pragma unroll
            for (int g = 0; g < 3; g++) {
                const float lo = Rb[((size_t)(2 * i2) * 3 + g) * 256];
                const float hi = Rb[((size_t)(2 * i2 + 1) * 3 + g) * 256];
                f16x2 p; p[0] = (_Float16)lo; p[1] = (_Float16)hi;
                Rr[g][i2] = p;
            }
        }
    }

    float hreg = 0.f;                      // fp32 carry for my o (threads t<256)
    float wxc0 = 0.f, wxc1 = 0.f, wxc2 = 0.f;
    if (t < 256) {
        const float* p = Wx + ((size_t)b * 12 + head * 3) * 256 + o;  // step 0
        wxc0 = p[0]; wxc1 = p[256]; wxc2 = p[512];
        h16[o] = (_Float16)0.f;
    }
    __syncthreads();

    float* outp = out + (size_t)b * 512 * 1024 + head * 256 + o;

    for (int step = 0; step < 512; step++) {
        // prefetch next step's wx (hidden under the dot loop)
        float wxn0 = 0.f, wxn1 = 0.f, wxn2 = 0.f;
        if (t < 256 && step < 511) {
            const float* p = Wx + (((size_t)(step + 1) * 64 + b) * 12 + head * 3) * 256 + o;
            wxn0 = p[0]; wxn1 = p[256]; wxn2 = p[512];
        }
        // ry partials over my K-half: 192 v_dot2_f32_f16 (h reads wave-broadcast)
        float az = 0.f, ar = 0.f, an = 0.f;
        const f16x8* hp = (const f16x8*)(h16 + ih * 128);
#pragma unroll
        for (int k = 0; k < 16; k++) {
            union { f16x8 v; f16x2 p[4]; } u;
            u.v = hp[k];
#pragma unroll
            for (int j = 0; j < 4; j++) {
                az = dot2f(Rr[0][k * 4 + j], u.p[j], az);
                ar = dot2f(Rr[1][k * 4 + j], u.p[j], ar);
                an = dot2f(Rr[2][k * 4 + j], u.p[j], an);
            }
        }
        red[ih][0][o] = az; red[ih][1][o] = ar; red[ih][2][o] = an;
        __syncthreads();
        if (t < 256) {
            const float z  = sigmoidf_(wxc0 + red[0][0][o] + red[1][0][o]);
            const float r  = sigmoidf_(wxc1 + red[0][1][o] + red[1][1][o]);
            const float n  = tanhf_(wxc2 + r * (red[0][2][o] + red[1][2][o]));
            const float hn = z * hreg + (1.f - z) * n;
            hreg = hn;
            outp[(size_t)step * 1024] = hn;
            h16[o] = (_Float16)hn;
        }
        wxc0 = wxn0; wxc1 = wxn1; wxc2 = wxn2;
        __syncthreads();
    }
}

// ---- hn = h[:, T-1, :] ----
__global__ __launch_bounds__(256) void copy_hn(float* __restrict__ out) {
    const int idx = blockIdx.x * 256 + threadIdx.x;  // 65536
    out[(size_t)64 * 512 * 1024 + idx] =
        out[((size_t)(idx >> 10) * 512 + 511) * 1024 + (idx & 1023)];
}

extern "C" void kernel_launch(void* const* d_in, const int* in_sizes, int n_in,
                              void* d_out, int out_size, void* d_ws, size_t ws_size,
                              hipStream_t stream) {
    (void)in_sizes; (void)n_in; (void)out_size; (void)ws_size;
    const float* inp = (const float*)d_in[0];
    const float* W   = (const float*)d_in[1];
    const float* bW  = (const float*)d_in[2];
    const float* R   = (const float*)d_in[3];
    const float* bR  = (const float*)d_in[4];
    float* out = (float*)d_out;

    // ws layout: A16 (64 MiB) | WT (6 MiB) | Wx f32 (384 MiB)
    _Float16* A16 = (_Float16*)d_ws;
    _Float16* WT  = (_Float16*)((char*)d_ws + 67108864);
    float*    Wx  = (float*)((char*)d_ws + 73400320);

    cast_to_f16<<<16384, 256, 0, stream>>>(inp, A16, 4194304);
    transpose_cast<<<dim3(96, 32), dim3(32, 8), 0, stream>>>(W, WT);
    gemm_wx<<<dim3(24, 256), 256, 0, stream>>>(A16, WT, bW, bR, Wx);
    scan_persist<<<256, 512, 0, stream>>>(R, Wx, out);
    copy_hn<<<256, 256, 0, stream>>>(out);
}

// Round 10
// 1033.986 us; speedup vs baseline: 1.0631x; 1.0390x over previous
//
#include <hip/hip_runtime.h>
#include <hip/hip_fp16.h>

// Problem: B=64, T=512, IN=1024, H=1024, NH=4, HD=256, NG=3
// out h: [B,T,H] then hn: [1,B,H]  (fp32)

typedef _Float16 f16x8 __attribute__((ext_vector_type(8)));
typedef _Float16 f16x2 __attribute__((ext_vector_type(2)));
typedef float    f32x4 __attribute__((ext_vector_type(4)));

#define AS1 __attribute__((address_space(1)))
#define AS3 __attribute__((address_space(3)))

__device__ __forceinline__ void async_ld16(const void* g, void* l) {
    __builtin_amdgcn_global_load_lds((const AS1 void*)g, (AS3 void*)l, 16, 0, 0);
}

__device__ __forceinline__ float sigmoidf_(float x) {
    return 1.f / (1.f + __expf(-x));
}
__device__ __forceinline__ float tanhf_(float x) {
    float e = __expf(-2.f * fabsf(x));
    float r = (1.f - e) / (1.f + e);
    return copysignf(r, x);
}

// f32 += dot(f16x2, f16x2), builtin only (no inline asm in the scan kernel).
#if defined(__has_builtin)
#if __has_builtin(__builtin_amdgcn_fdot2)
#define HAVE_FDOT2 1
#endif
#endif
__device__ __forceinline__ float dot2f(f16x2 a, f16x2 b, float c) {
#ifdef HAVE_FDOT2
    return __builtin_amdgcn_fdot2(a, b, c, false);
#else
    return c + (float)a[0] * (float)b[0] + (float)a[1] * (float)b[1];
#endif
}

// ---- input f32 -> f16 (vectorized) ----
__global__ __launch_bounds__(256) void cast_to_f16(const float* __restrict__ in,
                                                   _Float16* __restrict__ out, int n8) {
    int i = blockIdx.x * 256 + threadIdx.x;
    if (i >= n8) return;
    const float4* p = (const float4*)in;
    float4 a = p[2 * i], b = p[2 * i + 1];
    f16x8 r;
    r[0] = (_Float16)a.x; r[1] = (_Float16)a.y; r[2] = (_Float16)a.z; r[3] = (_Float16)a.w;
    r[4] = (_Float16)b.x; r[5] = (_Float16)b.y; r[6] = (_Float16)b.z; r[7] = (_Float16)b.w;
    *(f16x8*)(out + (size_t)i * 8) = r;
}

// ---- W [1024,3072] f32 -> W^T [3072,1024] f16 ----
__global__ __launch_bounds__(256) void transpose_cast(const float* __restrict__ W,
                                                      _Float16* __restrict__ WT) {
    __shared__ float tile[32][33];
    const int tx = threadIdx.x, ty = threadIdx.y;
    const int n0 = blockIdx.x * 32, k0 = blockIdx.y * 32;
#pragma unroll
    for (int j = 0; j < 32; j += 8)
        tile[ty + j][tx] = W[(size_t)(k0 + ty + j) * 3072 + n0 + tx];
    __syncthreads();
#pragma unroll
    for (int j = 0; j < 32; j += 8)
        WT[(size_t)(n0 + ty + j) * 1024 + k0 + tx] = (_Float16)tile[tx][ty + j];
}

// ---- GEMM: Wx[t][b][head][g][o] = (input @ W)[m=b*512+t][n] + bW[n] + bR[head][g][o]
__global__ __launch_bounds__(256) void gemm_wx(const _Float16* __restrict__ A,
                                               const _Float16* __restrict__ BT,
                                               const float* __restrict__ bW,
                                               const float* __restrict__ bR,
                                               float* __restrict__ Wx) {
    __shared__ _Float16 As[128 * 32];
    __shared__ _Float16 Bs[128 * 32];
    const int tid  = threadIdx.x;
    const int wave = tid >> 6, lane = tid & 63;
    const int m0 = blockIdx.y * 128, n0 = blockIdx.x * 128;
    const int wm = (wave >> 1) * 64, wn = (wave & 1) * 64;
    const int r16 = lane & 15, kq = lane >> 4;

    f32x4 acc[4][4];
#pragma unroll
    for (int m = 0; m < 4; m++)
#pragma unroll
        for (int n = 0; n < 4; n++) acc[m][n] = (f32x4){0.f, 0.f, 0.f, 0.f};

    const int srow = wave * 32 + (lane >> 2);
    const int scol = (lane & 3) * 8;

    for (int kt = 0; kt < 32; kt++) {
        const int k0 = kt * 32;
#pragma unroll
        for (int j = 0; j < 2; j++) {
            async_ld16(A  + (size_t)(m0 + srow + j * 16) * 1024 + k0 + scol,
                       As + (wave * 32 + j * 16) * 32);
            async_ld16(BT + (size_t)(n0 + srow + j * 16) * 1024 + k0 + scol,
                       Bs + (wave * 32 + j * 16) * 32);
        }
        __syncthreads();
        f16x8 af[4], bf[4];
#pragma unroll
        for (int m = 0; m < 4; m++) af[m] = *(const f16x8*)(As + (wm + m * 16 + r16) * 32 + kq * 8);
#pragma unroll
        for (int n = 0; n < 4; n++) bf[n] = *(const f16x8*)(Bs + (wn + n * 16 + r16) * 32 + kq * 8);
#pragma unroll
        for (int m = 0; m < 4; m++)
#pragma unroll
            for (int n = 0; n < 4; n++)
                acc[m][n] = __builtin_amdgcn_mfma_f32_16x16x32_f16(af[m], bf[n], acc[m][n], 0, 0, 0);
        __syncthreads();
    }

#pragma unroll
    for (int m = 0; m < 4; m++) {
        const int row0 = m0 + wm + m * 16 + (lane >> 4) * 4;
#pragma unroll
        for (int n = 0; n < 4; n++) {
            const int col  = n0 + wn + n * 16 + r16;
            const int g    = col >> 10, head = (col >> 8) & 3, o = col & 255;
            const float bias = bW[col] + bR[head * 768 + g * 256 + o];
#pragma unroll
            for (int q = 0; q < 4; q++) {
                const int rr = row0 + q;
                const int t = rr & 511, bb = rr >> 9;
                Wx[(((size_t)t * 64 + bb) * 12 + head * 3 + g) * 256 + o] = acc[m][n][q] + bias;
            }
        }
    }
}

// ---- persistent scan: one block per (b, head); 512 steps internal ----
// 1024 threads: o = t&255, ih = t>>8 (K-quarter). R2-R9 post-mortem: any
// per-thread R array >~96 regs was silently AGPR/scratch-backed (VGPR stuck at
// 64-128, perf invariant to all register attributes, WRITE_SIZE spill excess).
// Fix by construction: only z,r gates in registers (Rz+Rq = 64 regs/thread,
// comfortably < the 128 hard cap at 4 waves/SIMD); n-gate R lives in LDS
// (135 KB padded) and streams through the LDS pipe, overlapped with VALU.
__global__ __launch_bounds__(1024) void scan_persist(const float* __restrict__ R,
                                                     const float* __restrict__ Wx,
                                                     float* __restrict__ out) {
    extern __shared__ char smem[];
    _Float16* h16 = (_Float16*)smem;                       // 256 f16 (512 B)
    float*    red = (float*)(smem + 512);                  // [4][3][256] f32 (12 KB)
    _Float16* Rn  = (_Float16*)(smem + 512 + 12288);       // 256 rows x 264 f16 (528 B stride)

    const int head = blockIdx.x >> 6;
    const int b    = blockIdx.x & 63;
    const int t    = threadIdx.x;
    const int o    = t & 255;
    const int ih   = t >> 8;  // 0..3, wave-uniform

    // ---- stage R_n (gate 2) into LDS: Rn[row o2][i] ----
    for (int idx = t; idx < 65536; idx += 1024) {
        const int i = idx >> 8, o2 = idx & 255;
        Rn[o2 * 264 + i] = (_Float16)R[(((size_t)head * 256 + i) * 3 + 2) * 256 + o2];
    }

    // ---- z,r gate R slices in registers: i in [ih*64, ih*64+64), my o ----
    f16x2 Rz[32], Rq[32];
    {
        const float* Rb = R + (((size_t)head * 256 + ih * 64) * 3) * 256 + o;
#pragma unroll
        for (int i2 = 0; i2 < 32; i2++) {
            f16x2 pz, pq;
            pz[0] = (_Float16)Rb[((size_t)(2 * i2) * 3 + 0) * 256];
            pz[1] = (_Float16)Rb[((size_t)(2 * i2 + 1) * 3 + 0) * 256];
            pq[0] = (_Float16)Rb[((size_t)(2 * i2) * 3 + 1) * 256];
            pq[1] = (_Float16)Rb[((size_t)(2 * i2 + 1) * 3 + 1) * 256];
            Rz[i2] = pz; Rq[i2] = pq;
        }
    }

    float hreg = 0.f;                      // fp32 carry for my o (threads t<256)
    float wxc0 = 0.f, wxc1 = 0.f, wxc2 = 0.f;
    if (t < 256) {
        const float* p = Wx + ((size_t)b * 12 + head * 3) * 256 + o;  // step 0
        wxc0 = p[0]; wxc1 = p[256]; wxc2 = p[512];
        h16[o] = (_Float16)0.f;
    }
    __syncthreads();

    float* outp = out + (size_t)b * 512 * 1024 + head * 256 + o;
    const _Float16* RnRow = Rn + o * 264 + ih * 64;

    for (int step = 0; step < 512; step++) {
        // prefetch next step's wx (hidden under the dot loop)
        float wxn0 = 0.f, wxn1 = 0.f, wxn2 = 0.f;
        if (t < 256 && step < 511) {
            const float* p = Wx + (((size_t)(step + 1) * 64 + b) * 12 + head * 3) * 256 + o;
            wxn0 = p[0]; wxn1 = p[256]; wxn2 = p[512];
        }
        // ry partials over my i-quarter: z,r from regs; n from LDS
        float az = 0.f, ar = 0.f, an = 0.f;
        const f16x8* hp = (const f16x8*)(h16 + ih * 64);
        const f16x8* np = (const f16x8*)RnRow;
#pragma unroll
        for (int k = 0; k < 8; k++) {
            union { f16x8 v; f16x2 p[4]; } u, w;
            u.v = hp[k];
            w.v = np[k];
#pragma unroll
            for (int j = 0; j < 4; j++) {
                az = dot2f(Rz[k * 4 + j], u.p[j], az);
                ar = dot2f(Rq[k * 4 + j], u.p[j], ar);
                an = dot2f(w.p[j],        u.p[j], an);
            }
        }
        red[(ih * 3 + 0) * 256 + o] = az;
        red[(ih * 3 + 1) * 256 + o] = ar;
        red[(ih * 3 + 2) * 256 + o] = an;
        __syncthreads();
        if (t < 256) {
            const float sz = red[o] + red[768 + o] + red[1536 + o] + red[2304 + o];
            const float sr = red[256 + o] + red[1024 + o] + red[1792 + o] + red[2560 + o];
            const float sn = red[512 + o] + red[1280 + o] + red[2048 + o] + red[2816 + o];
            const float z  = sigmoidf_(wxc0 + sz);
            const float r  = sigmoidf_(wxc1 + sr);
            const float n  = tanhf_(wxc2 + r * sn);
            const float hn = z * hreg + (1.f - z) * n;
            hreg = hn;
            outp[(size_t)step * 1024] = hn;
            h16[o] = (_Float16)hn;
        }
        wxc0 = wxn0; wxc1 = wxn1; wxc2 = wxn2;
        __syncthreads();
    }
}

// ---- hn = h[:, T-1, :] ----
__global__ __launch_bounds__(256) void copy_hn(float* __restrict__ out) {
    const int idx = blockIdx.x * 256 + threadIdx.x;  // 65536
    out[(size_t)64 * 512 * 1024 + idx] =
        out[((size_t)(idx >> 10) * 512 + 511) * 1024 + (idx & 1023)];
}

extern "C" void kernel_launch(void* const* d_in, const int* in_sizes, int n_in,
                              void* d_out, int out_size, void* d_ws, size_t ws_size,
                              hipStream_t stream) {
    (void)in_sizes; (void)n_in; (void)out_size; (void)ws_size;
    const float* inp = (const float*)d_in[0];
    const float* W   = (const float*)d_in[1];
    const float* bW  = (const float*)d_in[2];
    const float* R   = (const float*)d_in[3];
    const float* bR  = (const float*)d_in[4];
    float* out = (float*)d_out;

    // ws layout: A16 (64 MiB) | WT (6 MiB) | Wx f32 (384 MiB)
    _Float16* A16 = (_Float16*)d_ws;
    _Float16* WT  = (_Float16*)((char*)d_ws + 67108864);
    float*    Wx  = (float*)((char*)d_ws + 73400320);

    const int scan_lds = 512 + 12288 + 256 * 264 * 2;  // 147968 B
    hipFuncSetAttribute((const void*)scan_persist,
                        hipFuncAttributeMaxDynamicSharedMemorySize, scan_lds);

    cast_to_f16<<<16384, 256, 0, stream>>>(inp, A16, 4194304);
    transpose_cast<<<dim3(96, 32), dim3(32, 8), 0, stream>>>(W, WT);
    gemm_wx<<<dim3(24, 256), 256, 0, stream>>>(A16, WT, bW, bR, Wx);
    scan_persist<<<256, 1024, scan_lds, stream>>>(R, Wx, out);
    copy_hn<<<256, 256, 0, stream>>>(out);
}